// Round 1
// baseline (168.534 us; speedup 1.0000x reference)
//
#include <hip/hip_runtime.h>

// Problem constants from the reference
#define BB 32
#define AA 3
#define HH 64
#define WW 64
#define NC 80
#define TT 50
#define THRESH 0.5f

// One wave (64 lanes) per (b,t) target.
__global__ __launch_bounds__(64) void class_loss_main(
    const float* __restrict__ output,    // (B, A, H, W, 5+NC) f32
    const float* __restrict__ anchors,   // (A, 2) f32
    const float* __restrict__ targets,   // (B, T, 5) f32
    float* __restrict__ ws)              // ws[0]=sum(ce*mask), ws[1]=cnt
{
    const int idx  = blockIdx.x;          // 0 .. B*T-1
    const int b    = idx / TT;
    const int t    = idx - b * TT;
    const int lane = threadIdx.x;         // 0..63 (wave64)

    // All lanes redundantly compute the per-target scalars (cheap; avoids bcast).
    const float* tgt = targets + (size_t)(b * TT + t) * 5;
    const float clsf = tgt[0];
    const float tx   = tgt[1];
    const float ty   = tgt[2];
    const float tw   = tgt[3] * (float)WW;
    const float th   = tgt[4] * (float)HH;

    int t_i = (int)(tx * (float)WW);  t_i = min(max(t_i, 0), WW - 1);
    int t_j = (int)(ty * (float)HH);  t_j = min(max(t_j, 0), HH - 1);

    // Best anchor by IoU (first-max semantics == jnp.argmax)
    float best_iou = -1.0f;
    int   best_a   = 0;
    #pragma unroll
    for (int a = 0; a < AA; ++a) {
        const float aw = anchors[a * 2 + 0];
        const float ah = anchors[a * 2 + 1];
        const float inter = fminf(aw, tw) * fminf(ah, th);
        const float uni   = aw * ah + tw * th - inter;
        const float iou   = inter / uni;
        if (iou > best_iou) { best_iou = iou; best_a = a; }
    }

    // mask == 0 -> contributes nothing to either sum or count.
    if (best_iou <= THRESH) return;   // wave-uniform: whole wave exits

    // Logit row: pred[b, best_a, t_j, t_i, :]  (skip first 5 channels)
    const size_t row_off =
        ((((size_t)b * AA + best_a) * HH + t_j) * WW + t_i) * (size_t)(5 + NC) + 5;
    const float* row = output + row_off;

    const float v0 = row[lane];
    const bool  has2 = (lane < NC - 64);              // lanes 0..15 -> class lane+64
    const float v1 = has2 ? row[lane + 64] : -INFINITY;

    // Wave-wide max (64-lane butterfly)
    float m = fmaxf(v0, v1);
    #pragma unroll
    for (int off = 32; off > 0; off >>= 1)
        m = fmaxf(m, __shfl_xor(m, off, 64));

    // Wave-wide sum of exp(x - m)
    float s = expf(v0 - m) + (has2 ? expf(v1 - m) : 0.0f);
    #pragma unroll
    for (int off = 32; off > 0; off >>= 1)
        s += __shfl_xor(s, off, 64);

    if (lane == 0) {
        const int cls = (int)clsf;                    // 0..NC-1, exact in f32
        const float lc = row[cls];                    // L1-hot reload
        const float ce = -(lc - m - logf(s));
        atomicAdd(&ws[0], ce);
        atomicAdd(&ws[1], 1.0f);
    }
}

__global__ void class_loss_finalize(const float* __restrict__ ws,
                                    float* __restrict__ out)
{
    const float cnt = ws[1];
    out[0] = (cnt > 0.0f) ? (ws[0] / cnt) : 0.0f;
}

extern "C" void kernel_launch(void* const* d_in, const int* in_sizes, int n_in,
                              void* d_out, int out_size, void* d_ws, size_t ws_size,
                              hipStream_t stream) {
    const float* output  = (const float*)d_in[0];   // (32,3,64,64,85)
    const float* anchors = (const float*)d_in[1];   // (3,2)
    const float* targets = (const float*)d_in[2];   // (32,50,5)
    float* ws  = (float*)d_ws;
    float* out = (float*)d_out;

    // d_ws is re-poisoned to 0xAA before every timed launch -> zero accumulators.
    hipMemsetAsync(d_ws, 0, 2 * sizeof(float), stream);

    class_loss_main<<<BB * TT, 64, 0, stream>>>(output, anchors, targets, ws);
    class_loss_finalize<<<1, 1, 0, stream>>>(ws, out);
}

// Round 2
// 163.889 us; speedup vs baseline: 1.0283x; 1.0283x over previous
//
#include <hip/hip_runtime.h>

// Problem constants from the reference
#define BB 32
#define AA 3
#define HH 64
#define WW 64
#define NC 80
#define TT 50
#define THRESH 0.5f

#define NTGT (BB * TT)          // 1600 targets
#define WAVES_PER_BLOCK 16      // 1024 threads/block
#define NBLOCKS (NTGT / WAVES_PER_BLOCK)  // 100 blocks

// ws layout: ws_f[0] = sum(ce*mask), ws_f[1] = cnt, ws_i[2] = ticket counter
__global__ __launch_bounds__(WAVES_PER_BLOCK * 64) void class_loss_fused(
    const float* __restrict__ output,    // (B, A, H, W, 5+NC) f32
    const float* __restrict__ anchors,   // (A, 2) f32
    const float* __restrict__ targets,   // (B, T, 5) f32
    float* __restrict__ ws,              // accumulators (pre-zeroed by memset)
    float* __restrict__ out)             // scalar result
{
    __shared__ float s_ce[WAVES_PER_BLOCK];
    __shared__ float s_cnt[WAVES_PER_BLOCK];

    const int wave = threadIdx.x >> 6;
    const int lane = threadIdx.x & 63;
    const int idx  = blockIdx.x * WAVES_PER_BLOCK + wave;   // target 0..1599
    const int b    = idx / TT;
    const int t    = idx - b * TT;

    // Per-target scalars (redundant across the wave; scalar-unit friendly).
    const float* tgt = targets + (size_t)(b * TT + t) * 5;
    const float clsf = tgt[0];
    const float tx   = tgt[1];
    const float ty   = tgt[2];
    const float tw   = tgt[3] * (float)WW;
    const float th   = tgt[4] * (float)HH;

    int t_i = (int)(tx * (float)WW);  t_i = min(max(t_i, 0), WW - 1);
    int t_j = (int)(ty * (float)HH);  t_j = min(max(t_j, 0), HH - 1);

    // Best anchor by IoU (strict > == jnp.argmax first-max semantics)
    float best_iou = -1.0f;
    int   best_a   = 0;
    #pragma unroll
    for (int a = 0; a < AA; ++a) {
        const float aw = anchors[a * 2 + 0];
        const float ah = anchors[a * 2 + 1];
        const float inter = fminf(aw, tw) * fminf(ah, th);
        const float uni   = aw * ah + tw * th - inter;
        const float iou   = inter / uni;
        if (iou > best_iou) { best_iou = iou; best_a = a; }
    }

    float ce = 0.0f, msk = 0.0f;
    if (best_iou > THRESH) {          // wave-uniform branch
        const size_t row_off =
            ((((size_t)b * AA + best_a) * HH + t_j) * WW + t_i) * (size_t)(5 + NC) + 5;
        const float* row = output + row_off;

        const float v0 = row[lane];                              // coalesced 64 floats
        const bool  has2 = (lane < NC - 64);                     // lanes 0..15
        const float v1 = has2 ? row[lane + 64] : -INFINITY;

        float m = fmaxf(v0, v1);
        #pragma unroll
        for (int off = 32; off > 0; off >>= 1)
            m = fmaxf(m, __shfl_xor(m, off, 64));

        float s = expf(v0 - m) + (has2 ? expf(v1 - m) : 0.0f);
        #pragma unroll
        for (int off = 32; off > 0; off >>= 1)
            s += __shfl_xor(s, off, 64);

        if (lane == 0) {
            const int cls = (int)clsf;                           // exact in f32
            const float lc = row[cls];                           // L1-hot
            ce  = -(lc - m - logf(s));
            msk = 1.0f;
        }
    }

    if (lane == 0) { s_ce[wave] = ce; s_cnt[wave] = msk; }
    __syncthreads();

    // Wave 0 reduces the 16 per-wave partials; one atomic pair per block.
    if (wave == 0) {
        float rc = (lane < WAVES_PER_BLOCK) ? s_ce[lane]  : 0.0f;
        float rn = (lane < WAVES_PER_BLOCK) ? s_cnt[lane] : 0.0f;
        #pragma unroll
        for (int off = 32; off > 0; off >>= 1) {
            rc += __shfl_xor(rc, off, 64);
            rn += __shfl_xor(rn, off, 64);
        }
        if (lane == 0) {
            atomicAdd(&ws[0], rc);
            atomicAdd(&ws[1], rn);
            __threadfence();                                    // release partials
            int* ticket = (int*)&ws[2];
            const int my = atomicAdd(ticket, 1);                // device-scope RMW
            if (my == NBLOCKS - 1) {                            // last block finalizes
                __threadfence();                                // acquire
                const float tot = atomicAdd(&ws[0], 0.0f);      // coherent reads
                const float cnt = atomicAdd(&ws[1], 0.0f);
                out[0] = (cnt > 0.0f) ? (tot / cnt) : 0.0f;
            }
        }
    }
}

extern "C" void kernel_launch(void* const* d_in, const int* in_sizes, int n_in,
                              void* d_out, int out_size, void* d_ws, size_t ws_size,
                              hipStream_t stream) {
    const float* output  = (const float*)d_in[0];   // (32,3,64,64,85)
    const float* anchors = (const float*)d_in[1];   // (3,2)
    const float* targets = (const float*)d_in[2];   // (32,50,5)
    float* ws  = (float*)d_ws;
    float* out = (float*)d_out;

    // Zero accumulators + ticket (d_ws is poisoned to 0xAA before every launch).
    hipMemsetAsync(d_ws, 0, 4 * sizeof(float), stream);

    class_loss_fused<<<NBLOCKS, WAVES_PER_BLOCK * 64, 0, stream>>>(
        output, anchors, targets, ws, out);
}